// Round 1
// baseline (162.074 us; speedup 1.0000x reference)
//
#include <hip/hip_runtime.h>
#include <hip/hip_fp16.h>
#include <hip/hip_cooperative_groups.h>

namespace cg = cooperative_groups;

#define NROWS 512
#define BHALF 256
#define DIM   512
#define TILE  64
#define DCHUNK 64
#define NCHUNK 8
#define NN (NROWS * NROWS)
#define SOFF (8 * NN)   // float offset of per-block distance-sum partials
// ws layout:
//   bytes [0 .. 8*NN*4)        : packed half2(l2_partial, l1_partial), one NN-buffer per d-chunk
//   floats [SOFF .. SOFF+1024) : per-block sum partials (512 S2, then 512 S1)

#define ACC(A, Bb, IV, JV)                                    \
    {                                                         \
        const float d_ = (IV) - (JV);                         \
        a2[A][Bb] = fmaf(d_, d_, a2[A][Bb]);                  \
        a1[A][Bb] += fabsf(d_);                               \
    }

#define STEP(DD)                                              \
    {                                                         \
        const float4 ivv = *(const float4*)&ai[DD][ty4];      \
        const float4 jvv = *(const float4*)&aj[DD][tx4];      \
        ACC(0, 0, ivv.x, jvv.x) ACC(0, 1, ivv.x, jvv.y)       \
        ACC(0, 2, ivv.x, jvv.z) ACC(0, 3, ivv.x, jvv.w)       \
        ACC(1, 0, ivv.y, jvv.x) ACC(1, 1, ivv.y, jvv.y)       \
        ACC(1, 2, ivv.y, jvv.z) ACC(1, 3, ivv.y, jvv.w)       \
        ACC(2, 0, ivv.z, jvv.x) ACC(2, 1, ivv.z, jvv.y)       \
        ACC(2, 2, ivv.z, jvv.z) ACC(2, 3, ivv.z, jvv.w)       \
        ACC(3, 0, ivv.w, jvv.x) ACC(3, 1, ivv.w, jvv.y)       \
        ACC(3, 2, ivv.w, jvv.z) ACC(3, 3, ivv.w, jvv.w)       \
    }

__device__ __forceinline__ unsigned int pack_h2(float l2v, float l1v) {
    const __half2 h = __halves2half2(__float2half_rn(l2v), __float2half_rn(l1v));
    union { __half2 h; unsigned int u; } c; c.h = h;
    return c.u;
}

__global__ __launch_bounds__(256) void k_fused(const float* __restrict__ src,
                                               const float* __restrict__ tgt,
                                               float* __restrict__ ws,
                                               float* __restrict__ out)
{
    __shared__ float ai[DCHUNK][TILE];   // 16 KB, transposed [d][row]
    __shared__ float aj[DCHUNK][TILE];   // 16 KB
    __shared__ float sred[8];

    const int tj = blockIdx.x;   // 0..7
    const int ti = blockIdx.y;   // 0..7
    const int dc = blockIdx.z;   // 0..7
    const int t  = threadIdx.x;
    const int bid = (dc * 8 + ti) * 8 + tj;   // 0..511

    // zero the output before any phase-2 atomics (ordering guaranteed by grid.sync)
    if (t == 0 && bid == 0) out[0] = 0.0f;

    // ================= phase 1: partial distances (verbatim from verified k_dist) =================
    {
        const int r  = t & 63;
        const int dg = t >> 6;
        const int gi = ti * TILE + r;
        const int gj = tj * TILE + r;
        const float* prow_i = (gi < BHALF ? src + (size_t)gi * DIM
                                          : tgt + (size_t)(gi - BHALF) * DIM) + dc * DCHUNK;
        const float* prow_j = (gj < BHALF ? src + (size_t)gj * DIM
                                          : tgt + (size_t)(gj - BHALF) * DIM) + dc * DCHUNK;
#pragma unroll
        for (int k = 0; k < 4; ++k) {
            const int d4 = dg * 4 + k;
            const float4 vi = *(const float4*)(prow_i + d4 * 4);
            const float4 vj = *(const float4*)(prow_j + d4 * 4);
            ai[d4 * 4 + 0][r] = vi.x; ai[d4 * 4 + 1][r] = vi.y;
            ai[d4 * 4 + 2][r] = vi.z; ai[d4 * 4 + 3][r] = vi.w;
            aj[d4 * 4 + 0][r] = vj.x; aj[d4 * 4 + 1][r] = vj.y;
            aj[d4 * 4 + 2][r] = vj.z; aj[d4 * 4 + 3][r] = vj.w;
        }
    }
    __syncthreads();

    const int tx  = t & 15;
    const int ty  = t >> 4;
    const int tx4 = tx * 4;
    const int ty4 = ty * 4;

    float a2[4][4], a1[4][4];
#pragma unroll
    for (int a = 0; a < 4; ++a)
#pragma unroll
        for (int b = 0; b < 4; ++b) { a2[a][b] = 0.f; a1[a][b] = 0.f; }

#pragma unroll 4
    for (int d = 0; d < DCHUNK; d += 2) {
        STEP(d)
        STEP(d + 1)
    }

    // ---- store packed half2(l2,l1) partial tiles: 4B/pair -> 8 MB total ----
    unsigned int* part_w = (unsigned int*)ws + (size_t)dc * NN;
    const int gj0 = tj * TILE + tx4;
#pragma unroll
    for (int a = 0; a < 4; ++a) {
        const int gi = ti * TILE + ty4 + a;
        const uint4 pk = make_uint4(pack_h2(a2[a][0], a1[a][0]),
                                    pack_h2(a2[a][1], a1[a][1]),
                                    pack_h2(a2[a][2], a1[a][2]),
                                    pack_h2(a2[a][3], a1[a][3]));
        *(uint4*)&part_w[(size_t)gi * NROWS + gj0] = pk;
    }

    // ---- block distance-sums (exact fp32) -> dedicated slots ----
    {
        float s2 = 0.f, s1 = 0.f;
#pragma unroll
        for (int a = 0; a < 4; ++a)
#pragma unroll
            for (int b = 0; b < 4; ++b) { s2 += a2[a][b]; s1 += a1[a][b]; }
#pragma unroll
        for (int off = 32; off > 0; off >>= 1) {
            s2 += __shfl_down(s2, off);
            s1 += __shfl_down(s1, off);
        }
        __syncthreads();
        float* red = &ai[0][0];
        const int wave = t >> 6;
        if ((t & 63) == 0) { red[wave * 2] = s2; red[wave * 2 + 1] = s1; }
        __syncthreads();
        if (t == 0) {
            ws[SOFF + bid]       = red[0] + red[2] + red[4] + red[6];
            ws[SOFF + 512 + bid] = red[1] + red[3] + red[5] + red[7];
        }
    }

    // ================= grid-wide barrier (device-scope visibility of partials) =================
    __threadfence();
    cg::this_grid().sync();

    // ================= phase 2: bw + exp kernels + reduce (k_mmd body over 512 blocks) =========
    float sp2 = ws[SOFF + t] + ws[SOFF + 256 + t];
    float sp1 = ws[SOFF + 512 + t] + ws[SOFF + 768 + t];
#pragma unroll
    for (int off = 32; off > 0; off >>= 1) {
        sp2 += __shfl_down(sp2, off);
        sp1 += __shfl_down(sp1, off);
    }
    if ((t & 63) == 0) { sred[(t >> 6) * 2] = sp2; sred[(t >> 6) * 2 + 1] = sp1; }
    __syncthreads();
    const float S2 = sred[0] + sred[2] + sred[4] + sred[6];
    const float S1 = sred[1] + sred[3] + sred[5] + sred[7];
    // bw = S/(N^2-N)/100 ; factor_t = (N^2-N)*100/S * 0.1^t
    const float r2 = 26163200.0f / S2;   // 512*511*100
    const float r1 = 26163200.0f / S1;

    const __half2* part = (const __half2*)ws;

    float acc = 0.f;
    const int base = bid * 512 + t;
#pragma unroll
    for (int q = 0; q < 2; ++q) {
        const int idx = base + q * 256;
        float l2 = 0.f, l1 = 0.f;
#pragma unroll
        for (int c = 0; c < NCHUNK; ++c) {
            const float2 f = __half22float2(part[(size_t)c * NN + idx]);
            l2 += f.x;
            l1 += f.y;
        }
        float kv = 0.f;
        float f2 = r2, f1 = r1;
#pragma unroll
        for (int tt = 0; tt < 5; ++tt) {
            kv += __expf(-l2 * f2) + __expf(-l1 * f1);
            f2 *= 0.1f;
            f1 *= 0.1f;
        }
        const int i = idx >> 9;
        const int j = idx & 511;
        const float sgn = (((i ^ j) & BHALF) == 0) ? 1.0f : -1.0f;
        acc += sgn * kv;
    }
#pragma unroll
    for (int off = 32; off > 0; off >>= 1) acc += __shfl_down(acc, off);

    __syncthreads();
    if ((t & 63) == 0) sred[t >> 6] = acc;
    __syncthreads();
    if (t == 0) {
        const float s = sred[0] + sred[1] + sred[2] + sred[3];
        atomicAdd(out, s * (1.0f / 65536.0f));
    }
}

extern "C" void kernel_launch(void* const* d_in, const int* in_sizes, int n_in,
                              void* d_out, int out_size, void* d_ws, size_t ws_size,
                              hipStream_t stream)
{
    const float* src = (const float*)d_in[0];
    const float* tgt = (const float*)d_in[1];
    float* ws  = (float*)d_ws;
    float* out = (float*)d_out;

    dim3 grid(8, 8, 8);
    dim3 block(256, 1, 1);
    void* args[] = { (void*)&src, (void*)&tgt, (void*)&ws, (void*)&out };
    hipLaunchCooperativeKernel((void*)k_fused, grid, block, args, 0u, stream);
}

// Round 2
// 82.345 us; speedup vs baseline: 1.9682x; 1.9682x over previous
//
#include <hip/hip_runtime.h>
#include <hip/hip_fp16.h>

#define NROWS 512
#define BHALF 256
#define DIM   512
#define TI    128        // block tile (i and j)
#define DC    32         // d-chunk per block
#define NCHUNK 16
#define NN (NROWS * NROWS)
#define SOFF (NCHUNK * NN)   // float offset of per-block distance-sum partials
// ws layout:
//   bytes  [0 .. 16*NN*4)       : packed half2(l2_partial, l1_partial), one NN-buffer per d-chunk
//   floats [SOFF .. SOFF+1024)  : per-block sum partials (256 S2 at +0, 256 S1 at +512)

#define PAIR(A, B, IV, JV)                                    \
    {                                                         \
        const float d_ = (IV) - (JV);                         \
        a2[A][B] = fmaf(d_, d_, a2[A][B]);                    \
        a1[A][B] += fabsf(d_);                                \
    }

#define ROW(A, IVC)                                           \
    PAIR(A, 0, IVC, jva.x) PAIR(A, 1, IVC, jva.y)             \
    PAIR(A, 2, IVC, jva.z) PAIR(A, 3, IVC, jva.w)             \
    PAIR(A, 4, IVC, jvb.x) PAIR(A, 5, IVC, jvb.y)             \
    PAIR(A, 6, IVC, jvb.z) PAIR(A, 7, IVC, jvb.w)

__device__ __forceinline__ unsigned int pack_h2(float l2v, float l1v) {
    const __half2 h = __halves2half2(__float2half_rn(l2v), __float2half_rn(l1v));
    union { __half2 h; unsigned int u; } c; c.h = h;
    return c.u;
}

__global__ __launch_bounds__(512, 2) void k_dist(const float* __restrict__ src,
                                                 const float* __restrict__ tgt,
                                                 float* __restrict__ ws,
                                                 float* __restrict__ out)
{
    __shared__ float ai[DC][TI];   // 16 KB, transposed [d][row]
    __shared__ float aj[DC][TI];   // 16 KB

    const int tj = blockIdx.x;   // 0..3
    const int ti = blockIdx.y;   // 0..3
    const int dc = blockIdx.z;   // 0..15
    const int t  = threadIdx.x;  // 0..511

    if (t == 0 && tj == 0 && ti == 0 && dc == 0) out[0] = 0.0f;

    // ---- stage global -> LDS (transposed [d][row]; store banks = row%32 -> 2-way, free) ----
    {
        const int r2   = t & 255;            // 0..255 (uniform role per wave)
        const int half = t >> 8;             // 0..1 -> d-halves
        const int isJ  = r2 >> 7;            // waves 0,1,4,5 -> i; 2,3,6,7 -> j
        const int rr   = r2 & 127;
        const int grow = (isJ ? tj : ti) * TI + rr;
        const float* prow = (grow < BHALF ? src + (size_t)grow * DIM
                                          : tgt + (size_t)(grow - BHALF) * DIM)
                            + dc * DC + half * 16;
        float (*dst)[TI] = isJ ? aj : ai;
#pragma unroll
        for (int k = 0; k < 4; ++k) {
            const float4 v = *(const float4*)(prow + k * 4);
            const int d0 = half * 16 + k * 4;
            dst[d0 + 0][rr] = v.x; dst[d0 + 1][rr] = v.y;
            dst[d0 + 2][rr] = v.z; dst[d0 + 3][rr] = v.w;
        }
    }
    __syncthreads();

    const int jx  = t & 15;      // j-group
    const int iy  = t >> 4;      // i-group 0..31
    const int jx4 = jx * 4;      // j-cols jx4..jx4+3 and jx4+64..jx4+67 (both 2-way alias = free)
    const int iy4 = iy * 4;

    float a2[4][8], a1[4][8];
#pragma unroll
    for (int a = 0; a < 4; ++a)
#pragma unroll
        for (int b = 0; b < 8; ++b) { a2[a][b] = 0.f; a1[a][b] = 0.f; }

    float4 iv  = *(const float4*)&ai[0][iy4];
    float4 jva = *(const float4*)&aj[0][jx4];
    float4 jvb = *(const float4*)&aj[0][jx4 + 64];
#pragma unroll 4
    for (int d = 0; d < DC; ++d) {
        float4 niv, nja, njb;
        if (d + 1 < DC) {
            niv = *(const float4*)&ai[d + 1][iy4];
            nja = *(const float4*)&aj[d + 1][jx4];
            njb = *(const float4*)&aj[d + 1][jx4 + 64];
        }
        ROW(0, iv.x) ROW(1, iv.y) ROW(2, iv.z) ROW(3, iv.w)
        if (d + 1 < DC) { iv = niv; jva = nja; jvb = njb; }
    }

    // ---- store packed half2(l2,l1) partial tiles: two uint4 per i-row ----
    unsigned int* part_w = (unsigned int*)ws + (size_t)dc * NN;
    const int gj0 = tj * TI + jx4;
#pragma unroll
    for (int a = 0; a < 4; ++a) {
        const int gi = ti * TI + iy4 + a;
        const uint4 pk0 = make_uint4(pack_h2(a2[a][0], a1[a][0]),
                                     pack_h2(a2[a][1], a1[a][1]),
                                     pack_h2(a2[a][2], a1[a][2]),
                                     pack_h2(a2[a][3], a1[a][3]));
        const uint4 pk1 = make_uint4(pack_h2(a2[a][4], a1[a][4]),
                                     pack_h2(a2[a][5], a1[a][5]),
                                     pack_h2(a2[a][6], a1[a][6]),
                                     pack_h2(a2[a][7], a1[a][7]));
        *(uint4*)&part_w[(size_t)gi * NROWS + gj0]      = pk0;
        *(uint4*)&part_w[(size_t)gi * NROWS + gj0 + 64] = pk1;
    }

    // ---- block distance-sums (exact fp32) -> dedicated slots ----
    float s2 = 0.f, s1 = 0.f;
#pragma unroll
    for (int a = 0; a < 4; ++a)
#pragma unroll
        for (int b = 0; b < 8; ++b) { s2 += a2[a][b]; s1 += a1[a][b]; }
#pragma unroll
    for (int off = 32; off > 0; off >>= 1) {
        s2 += __shfl_down(s2, off);
        s1 += __shfl_down(s1, off);
    }
    __syncthreads();
    float* red = &ai[0][0];
    const int wave = t >> 6;   // 0..7
    if ((t & 63) == 0) { red[wave * 2] = s2; red[wave * 2 + 1] = s1; }
    __syncthreads();
    if (t == 0) {
        const int bid = (dc * 4 + ti) * 4 + tj;   // 0..255
        float r2s = 0.f, r1s = 0.f;
#pragma unroll
        for (int w = 0; w < 8; ++w) { r2s += red[w * 2]; r1s += red[w * 2 + 1]; }
        ws[SOFF + bid]       = r2s;
        ws[SOFF + 512 + bid] = r1s;
    }
}

__global__ __launch_bounds__(256) void k_mmd(const float* __restrict__ ws,
                                             float* __restrict__ out)
{
    const int t = threadIdx.x;
    __shared__ float sred[8];

    // ---- reduce 256+256 block partials to S2, S1 ----
    float sp2 = ws[SOFF + t];
    float sp1 = ws[SOFF + 512 + t];
#pragma unroll
    for (int off = 32; off > 0; off >>= 1) {
        sp2 += __shfl_down(sp2, off);
        sp1 += __shfl_down(sp1, off);
    }
    if ((t & 63) == 0) { sred[(t >> 6) * 2] = sp2; sred[(t >> 6) * 2 + 1] = sp1; }
    __syncthreads();
    const float S2 = sred[0] + sred[2] + sred[4] + sred[6];
    const float S1 = sred[1] + sred[3] + sred[5] + sred[7];
    // bw = S/(N^2-N)/100 ; factor_t = (N^2-N)*100/S * 0.1^t
    const float r2 = 26163200.0f / S2;   // 512*511*100
    const float r1 = 26163200.0f / S1;

    const __half2* part = (const __half2*)ws;

    float acc = 0.f;
    const int base = blockIdx.x * 1024 + t;
#pragma unroll
    for (int q = 0; q < 4; ++q) {
        const int idx = base + q * 256;
        float l2 = 0.f, l1 = 0.f;
#pragma unroll
        for (int c = 0; c < NCHUNK; ++c) {
            const float2 f = __half22float2(part[(size_t)c * NN + idx]);
            l2 += f.x;
            l1 += f.y;
        }
        float kv = 0.f;
        float f2 = r2, f1 = r1;
#pragma unroll
        for (int tt = 0; tt < 5; ++tt) {
            kv += __expf(-l2 * f2) + __expf(-l1 * f1);
            f2 *= 0.1f;
            f1 *= 0.1f;
        }
        const int i = idx >> 9;
        const int j = idx & 511;
        const float sgn = (((i ^ j) & BHALF) == 0) ? 1.0f : -1.0f;
        acc += sgn * kv;
    }
#pragma unroll
    for (int off = 32; off > 0; off >>= 1) acc += __shfl_down(acc, off);

    __syncthreads();
    if ((t & 63) == 0) sred[t >> 6] = acc;
    __syncthreads();
    if (t == 0) {
        const float s = sred[0] + sred[1] + sred[2] + sred[3];
        atomicAdd(out, s * (1.0f / 65536.0f));
    }
}

extern "C" void kernel_launch(void* const* d_in, const int* in_sizes, int n_in,
                              void* d_out, int out_size, void* d_ws, size_t ws_size,
                              hipStream_t stream)
{
    const float* src = (const float*)d_in[0];
    const float* tgt = (const float*)d_in[1];
    float* ws  = (float*)d_ws;
    float* out = (float*)d_out;

    dim3 g1(4, 4, 16);
    k_dist<<<g1, 512, 0, stream>>>(src, tgt, ws, out);
    k_mmd<<<256, 256, 0, stream>>>(ws, out);
}

// Round 3
// 80.879 us; speedup vs baseline: 2.0039x; 1.0181x over previous
//
#include <hip/hip_runtime.h>
#include <hip/hip_fp16.h>

#define NROWS 512
#define BHALF 256
#define DIM   512
#define TILE  64
#define DCHUNK 64
#define NCHUNK 8
#define NN (NROWS * NROWS)
#define SOFF (8 * NN)   // float offset of per-block distance-sum partials
// ws layout:
//   bytes [0 .. 8*NN*4)        : packed half2(l2_partial, l1_partial), one NN-buffer per d-chunk
//   floats [SOFF .. SOFF+1024) : per-block sum partials (512 S2, then 512 S1)

#define ACC(A, Bb, IV, JV)                                    \
    {                                                         \
        const float d_ = (IV) - (JV);                         \
        a2[A][Bb] = fmaf(d_, d_, a2[A][Bb]);                  \
        a1[A][Bb] += fabsf(d_);                               \
    }

#define STEP(DD)                                              \
    {                                                         \
        const float4 ivv = *(const float4*)&ai[DD][ty4];      \
        const float4 jvv = *(const float4*)&aj[DD][tx4];      \
        ACC(0, 0, ivv.x, jvv.x) ACC(0, 1, ivv.x, jvv.y)       \
        ACC(0, 2, ivv.x, jvv.z) ACC(0, 3, ivv.x, jvv.w)       \
        ACC(1, 0, ivv.y, jvv.x) ACC(1, 1, ivv.y, jvv.y)       \
        ACC(1, 2, ivv.y, jvv.z) ACC(1, 3, ivv.y, jvv.w)       \
        ACC(2, 0, ivv.z, jvv.x) ACC(2, 1, ivv.z, jvv.y)       \
        ACC(2, 2, ivv.z, jvv.z) ACC(2, 3, ivv.z, jvv.w)       \
        ACC(3, 0, ivv.w, jvv.x) ACC(3, 1, ivv.w, jvv.y)       \
        ACC(3, 2, ivv.w, jvv.z) ACC(3, 3, ivv.w, jvv.w)       \
    }

__device__ __forceinline__ unsigned int pack_h2(float l2v, float l1v) {
    const __half2 h = __halves2half2(__float2half_rn(l2v), __float2half_rn(l1v));
    union { __half2 h; unsigned int u; } c; c.h = h;
    return c.u;
}

// ---------------- k_dist: EXACT round-0 version (proven best) ----------------
__global__ __launch_bounds__(256) void k_dist(const float* __restrict__ src,
                                              const float* __restrict__ tgt,
                                              float* __restrict__ ws,
                                              float* __restrict__ out)
{
    __shared__ float ai[DCHUNK][TILE];   // 16 KB, transposed [d][row]
    __shared__ float aj[DCHUNK][TILE];   // 16 KB

    const int tj = blockIdx.x;   // 0..7
    const int ti = blockIdx.y;   // 0..7
    const int dc = blockIdx.z;   // 0..7
    const int t  = threadIdx.x;

    if (t == 0 && tj == 0 && ti == 0 && dc == 0) out[0] = 0.0f;

    {
        const int r  = t & 63;
        const int dg = t >> 6;
        const int gi = ti * TILE + r;
        const int gj = tj * TILE + r;
        const float* prow_i = (gi < BHALF ? src + (size_t)gi * DIM
                                          : tgt + (size_t)(gi - BHALF) * DIM) + dc * DCHUNK;
        const float* prow_j = (gj < BHALF ? src + (size_t)gj * DIM
                                          : tgt + (size_t)(gj - BHALF) * DIM) + dc * DCHUNK;
#pragma unroll
        for (int k = 0; k < 4; ++k) {
            const int d4 = dg * 4 + k;
            const float4 vi = *(const float4*)(prow_i + d4 * 4);
            const float4 vj = *(const float4*)(prow_j + d4 * 4);
            ai[d4 * 4 + 0][r] = vi.x; ai[d4 * 4 + 1][r] = vi.y;
            ai[d4 * 4 + 2][r] = vi.z; ai[d4 * 4 + 3][r] = vi.w;
            aj[d4 * 4 + 0][r] = vj.x; aj[d4 * 4 + 1][r] = vj.y;
            aj[d4 * 4 + 2][r] = vj.z; aj[d4 * 4 + 3][r] = vj.w;
        }
    }
    __syncthreads();

    const int tx  = t & 15;
    const int ty  = t >> 4;
    const int tx4 = tx * 4;
    const int ty4 = ty * 4;

    float a2[4][4], a1[4][4];
#pragma unroll
    for (int a = 0; a < 4; ++a)
#pragma unroll
        for (int b = 0; b < 4; ++b) { a2[a][b] = 0.f; a1[a][b] = 0.f; }

#pragma unroll 4
    for (int d = 0; d < DCHUNK; d += 2) {
        STEP(d)
        STEP(d + 1)
    }

    // ---- store packed half2(l2,l1) partial tiles: 4B/pair -> 8 MB total ----
    unsigned int* part = (unsigned int*)ws + (size_t)dc * NN;
    const int gj0 = tj * TILE + tx4;
#pragma unroll
    for (int a = 0; a < 4; ++a) {
        const int gi = ti * TILE + ty4 + a;
        const uint4 pk = make_uint4(pack_h2(a2[a][0], a1[a][0]),
                                    pack_h2(a2[a][1], a1[a][1]),
                                    pack_h2(a2[a][2], a1[a][2]),
                                    pack_h2(a2[a][3], a1[a][3]));
        *(uint4*)&part[(size_t)gi * NROWS + gj0] = pk;
    }

    // ---- block distance-sums (exact fp32) -> dedicated slots ----
    float s2 = 0.f, s1 = 0.f;
#pragma unroll
    for (int a = 0; a < 4; ++a)
#pragma unroll
        for (int b = 0; b < 4; ++b) { s2 += a2[a][b]; s1 += a1[a][b]; }
#pragma unroll
    for (int off = 32; off > 0; off >>= 1) {
        s2 += __shfl_down(s2, off);
        s1 += __shfl_down(s1, off);
    }
    __syncthreads();
    float* red = &ai[0][0];
    const int wave = t >> 6;
    if ((t & 63) == 0) { red[wave * 2] = s2; red[wave * 2 + 1] = s1; }
    __syncthreads();
    if (t == 0) {
        const int bid = (dc * 8 + ti) * 8 + tj;
        ws[SOFF + bid]       = red[0] + red[2] + red[4] + red[6];
        ws[SOFF + 512 + bid] = red[1] + red[3] + red[5] + red[7];
    }
}

// ---------------- k_mmd: high-occupancy, batched-load rewrite ----------------
// 512 blocks x 256 thr (2 waves/SIMD). Each thread: 2 consecutive idx,
// all 8 chunk loads issued as dwordx2 BEFORE any use -> one latency exposure.
__global__ __launch_bounds__(256) void k_mmd(const float* __restrict__ ws,
                                             float* __restrict__ out)
{
    const int t = threadIdx.x;
    __shared__ float sred[8];

    // ---- reduce 512+512 block partials to S2, S1 ----
    float sp2 = ws[SOFF + t] + ws[SOFF + 256 + t];
    float sp1 = ws[SOFF + 512 + t] + ws[SOFF + 768 + t];
#pragma unroll
    for (int off = 32; off > 0; off >>= 1) {
        sp2 += __shfl_down(sp2, off);
        sp1 += __shfl_down(sp1, off);
    }
    if ((t & 63) == 0) { sred[(t >> 6) * 2] = sp2; sred[(t >> 6) * 2 + 1] = sp1; }
    __syncthreads();
    const float S2 = sred[0] + sred[2] + sred[4] + sred[6];
    const float S1 = sred[1] + sred[3] + sred[5] + sred[7];
    // bw = S/(N^2-N)/100 ; factor_t = (N^2-N)*100/S * 0.1^t
    const float r2 = 26163200.0f / S2;   // 512*511*100
    const float r1 = 26163200.0f / S1;

    // ---- batched loads: 2 consecutive idx per thread, 8 chunks, dwordx2 each ----
    const unsigned int* pu = (const unsigned int*)ws;
    const int base2 = (blockIdx.x * 256 + t) * 2;   // even idx, 0..262142
    uint2 v[NCHUNK];
#pragma unroll
    for (int c = 0; c < NCHUNK; ++c)
        v[c] = *(const uint2*)(pu + (size_t)c * NN + base2);

    float acc = 0.f;
#pragma unroll
    for (int s = 0; s < 2; ++s) {
        float l2 = 0.f, l1 = 0.f;
#pragma unroll
        for (int c = 0; c < NCHUNK; ++c) {
            union { unsigned int u; __half2 h; } cv;
            cv.u = s ? v[c].y : v[c].x;
            const float2 f = __half22float2(cv.h);
            l2 += f.x;
            l1 += f.y;
        }
        float kv = 0.f;
        float f2 = r2, f1 = r1;
#pragma unroll
        for (int tt = 0; tt < 5; ++tt) {
            kv += __expf(-l2 * f2) + __expf(-l1 * f1);
            f2 *= 0.1f;
            f1 *= 0.1f;
        }
        const int idx = base2 + s;
        const int i = idx >> 9;
        const int j = idx & 511;
        acc += ((((i ^ j) & BHALF) == 0) ? kv : -kv);
    }
#pragma unroll
    for (int off = 32; off > 0; off >>= 1) acc += __shfl_down(acc, off);

    __syncthreads();
    if ((t & 63) == 0) sred[t >> 6] = acc;
    __syncthreads();
    if (t == 0) {
        const float s = sred[0] + sred[1] + sred[2] + sred[3];
        atomicAdd(out, s * (1.0f / 65536.0f));
    }
}

extern "C" void kernel_launch(void* const* d_in, const int* in_sizes, int n_in,
                              void* d_out, int out_size, void* d_ws, size_t ws_size,
                              hipStream_t stream)
{
    const float* src = (const float*)d_in[0];
    const float* tgt = (const float*)d_in[1];
    float* ws  = (float*)d_ws;
    float* out = (float*)d_out;

    dim3 g1(8, 8, 8);
    k_dist<<<g1, 256, 0, stream>>>(src, tgt, ws, out);
    k_mmd<<<512, 256, 0, stream>>>(ws, out);
}